// Round 1
// 34.397 us; speedup vs baseline: 1.0183x; 1.0183x over previous
//
#include <hip/hip_runtime.h>

#define Q 8                // x-slab blocks per person (5 stored planes each)
#define NR 8               // register-held verts per thread (covers V <= 8192)
#define QCAP 8192          // LDS work-queue capacity (verts; 3 floats each)

// ---------------------------------------------------------------------------
// Fused kernel: one block per (person, x-slab). 1024 threads.
// R13 change vs R12-2x: own-person verts are loaded from global ONCE into
// registers (NR x float3 per thread); bounds AND the build filter both run
// from registers, and the work-queue stores world coords so the scatter
// drain never touches global memory. Arithmetic is bit-identical to R12.
// ---------------------------------------------------------------------------
__global__ __launch_bounds__(1024) void k_fused(const float* __restrict__ verts,
                                                const float* __restrict__ trans,
                                                float* __restrict__ part,
                                                int V, int n,
                                                const int* __restrict__ pP) {
    __shared__ int   sgrid[5 * 1024];      // [xi-xlo][yi][zi] d^2 bits, 20 KB
    __shared__ float qf[3 * QCAP];         // world coords queue, 96 KB
    __shared__ int   qc;
    __shared__ float red[16][6];
    __shared__ float c4[4];
    __shared__ float racc[16];

    int bq  = blockIdx.x;
    int p   = bq / Q;
    int q   = bq - p * Q;
    int xlo = q * 4;
    int xhi = min(31, xlo + 4);
    int tid = threadIdx.x, lane = tid & 63, wave = tid >> 6;

    for (int k = tid; k < 5 * 1024; k += 1024) sgrid[k] = 0x7F7F7F7F;
    if (tid == 0) qc = 0;

    const float* vp = verts + (size_t)p * V * 3;

    // --- 1. load own verts into registers + bounds ------------------------
    float rx[NR], ry[NR], rz[NR];
    {
        float mnx = 3.4e38f, mny = 3.4e38f, mnz = 3.4e38f;
        float mxx = -3.4e38f, mxy = -3.4e38f, mxz = -3.4e38f;
        #pragma unroll
        for (int r = 0; r < NR; ++r) {
            int j = tid + (r << 10);
            if (j < V) {
                float x = vp[3 * j + 0], y = vp[3 * j + 1], z = vp[3 * j + 2];
                rx[r] = x; ry[r] = y; rz[r] = z;
                mnx = fminf(mnx, x); mxx = fmaxf(mxx, x);
                mny = fminf(mny, y); mxy = fmaxf(mxy, y);
                mnz = fminf(mnz, z); mxz = fmaxf(mxz, z);
            } else {
                rx[r] = 0.0f; ry[r] = 0.0f; rz[r] = 0.0f;
            }
        }
        // streamed tail (only if V > NR*1024; never taken for V=6890)
        for (int j = tid + (NR << 10); j < V; j += 1024) {
            float x = vp[3 * j + 0], y = vp[3 * j + 1], z = vp[3 * j + 2];
            mnx = fminf(mnx, x); mxx = fmaxf(mxx, x);
            mny = fminf(mny, y); mxy = fmaxf(mxy, y);
            mnz = fminf(mnz, z); mxz = fmaxf(mxz, z);
        }
        for (int m = 32; m > 0; m >>= 1) {
            mnx = fminf(mnx, __shfl_xor(mnx, m)); mxx = fmaxf(mxx, __shfl_xor(mxx, m));
            mny = fminf(mny, __shfl_xor(mny, m)); mxy = fmaxf(mxy, __shfl_xor(mxy, m));
            mnz = fminf(mnz, __shfl_xor(mnz, m)); mxz = fmaxf(mxz, __shfl_xor(mxz, m));
        }
        if (lane == 0) {
            red[wave][0] = mnx; red[wave][1] = mny; red[wave][2] = mnz;
            red[wave][3] = mxx; red[wave][4] = mxy; red[wave][5] = mxz;
        }
        __syncthreads();
        if (tid == 0) {
            float a0 = red[0][0], a1 = red[0][1], a2 = red[0][2];
            float b0 = red[0][3], b1 = red[0][4], b2 = red[0][5];
            for (int w = 1; w < 16; ++w) {
                a0 = fminf(a0, red[w][0]); a1 = fminf(a1, red[w][1]); a2 = fminf(a2, red[w][2]);
                b0 = fmaxf(b0, red[w][3]); b1 = fmaxf(b1, red[w][4]); b2 = fmaxf(b2, red[w][5]);
            }
            float tx = trans[p * 3 + 0], ty = trans[p * 3 + 1], tz = trans[p * 3 + 2];
            float scale = 0.6f * fmaxf(b0 - a0, fmaxf(b1 - a1, b2 - a2));  // (1+0.2)*0.5
            c4[0] = 0.5f * (a0 + b0) + tx;
            c4[1] = 0.5f * (a1 + b1) + ty;
            c4[2] = 0.5f * (a2 + b2) + tz;
            c4[3] = scale;
        }
        __syncthreads();
    }
    float cx = c4[0], cy = c4[1], cz = c4[2], s = c4[3];
    float inv = 1.0f / s;
    float tx = trans[p * 3 + 0], ty = trans[p * 3 + 1], tz = trans[p * 3 + 2];
    float rg = (4.65f * inv) * 1.0005f + 0.005f;
    const float step = 2.0f / 31.0f;

    // --- 2. build: filter from registers, queue world coords --------------
    #pragma unroll
    for (int r = 0; r < NR; ++r) {
        int j = tid + (r << 10);
        bool in = (j < V);
        float wx = rx[r] + tx;
        float gvx = ((wx - cx) * inv + 1.0f) * 15.5f;
        int x0v = max(0, (int)ceilf(gvx - rg));
        int x1v = min(31, (int)floorf(gvx + rg));
        bool pass = in && (x0v <= x1v) && (x0v <= xhi) && (x1v >= xlo);
        unsigned long long m = __ballot(pass);
        if (m) {
            int ldr = (int)__ffsll((long long)m) - 1;
            int bofs = 0;
            if (lane == ldr) bofs = atomicAdd(&qc, (int)__popcll(m));
            bofs = __shfl(bofs, ldr);
            if (pass) {
                int idx = bofs + (int)__popcll(m & ((1ull << lane) - 1ull));
                qf[3 * idx + 0] = wx;
                qf[3 * idx + 1] = ry[r] + ty;
                qf[3 * idx + 2] = rz[r] + tz;
            }
        }
    }
    __syncthreads();
    {
        int cnt = qc;
        for (int e = tid; e < cnt; e += 1024) {
            float wx = qf[3 * e + 0];
            float wy = qf[3 * e + 1];
            float wz = qf[3 * e + 2];
            float gvx = ((wx - cx) * inv + 1.0f) * 15.5f;
            float gvy = ((wy - cy) * inv + 1.0f) * 15.5f;
            float gvz = ((wz - cz) * inv + 1.0f) * 15.5f;
            int x0 = max(xlo, (int)ceilf(gvx - rg)), x1 = min(xhi, (int)floorf(gvx + rg));
            int y0 = max(0, (int)ceilf(gvy - rg)),   y1 = min(31, (int)floorf(gvy + rg));
            int z0 = max(0, (int)ceilf(gvz - rg)),   z1 = min(31, (int)floorf(gvz + rg));
            for (int xi = x0; xi <= x1; ++xi) {
                float qx = fmaf((float)xi, step, -1.0f) * s + cx;
                float dx = qx - wx;
                float dx2 = dx * dx;
                if (dx2 >= 0.09f) continue;
                for (int yi = y0; yi <= y1; ++yi) {
                    float qy = fmaf((float)yi, step, -1.0f) * s + cy;
                    float dy = qy - wy;
                    float dxy = fmaf(dy, dy, dx2);
                    if (dxy >= 0.09f) continue;
                    for (int zi = z0; zi <= z1; ++zi) {
                        float qz = fmaf((float)zi, step, -1.0f) * s + cz;
                        float dz = qz - wz;
                        float d2 = fmaf(dz, dz, dxy);
                        if (d2 < 0.09f)
                            atomicMin(&sgrid[((xi - xlo) << 10) | (yi << 5) | zi],
                                      __float_as_int(d2));
                    }
                }
            }
        }
        // streamed tail (V > NR*1024 only): direct scatter, no queue
        for (int j = tid + (NR << 10); j < V; j += 1024) {
            float wx = vp[3 * j + 0] + tx;
            float wy = vp[3 * j + 1] + ty;
            float wz = vp[3 * j + 2] + tz;
            float gvx = ((wx - cx) * inv + 1.0f) * 15.5f;
            float gvy = ((wy - cy) * inv + 1.0f) * 15.5f;
            float gvz = ((wz - cz) * inv + 1.0f) * 15.5f;
            int x0 = max(xlo, (int)ceilf(gvx - rg)), x1 = min(xhi, (int)floorf(gvx + rg));
            int y0 = max(0, (int)ceilf(gvy - rg)),   y1 = min(31, (int)floorf(gvy + rg));
            int z0 = max(0, (int)ceilf(gvz - rg)),   z1 = min(31, (int)floorf(gvz + rg));
            for (int xi = x0; xi <= x1; ++xi) {
                float qx = fmaf((float)xi, step, -1.0f) * s + cx;
                float dx = qx - wx;
                float dx2 = dx * dx;
                if (dx2 >= 0.09f) continue;
                for (int yi = y0; yi <= y1; ++yi) {
                    float qy = fmaf((float)yi, step, -1.0f) * s + cy;
                    float dy = qy - wy;
                    float dxy = fmaf(dy, dy, dx2);
                    if (dxy >= 0.09f) continue;
                    for (int zi = z0; zi <= z1; ++zi) {
                        float qz = fmaf((float)zi, step, -1.0f) * s + cz;
                        float dz = qz - wz;
                        float d2 = fmaf(dz, dz, dxy);
                        if (d2 < 0.09f)
                            atomicMin(&sgrid[((xi - xlo) << 10) | (yi << 5) | zi],
                                      __float_as_int(d2));
                    }
                }
            }
        }
        __syncthreads();
    }

    // --- 3. sample (2x unrolled): verts owned by this slab (x0>>2 == q) ---
    int P = *pP;
    int f = p / P, iloc = p - f * P;
    float acc = 0.0f;
    for (int jp = 0; jp < P; ++jp) {
        if (jp == iloc) continue;
        int pj = f * P + jp;
        const float* vj = verts + (size_t)pj * V * 3;
        float tjx = trans[pj * 3 + 0], tjy = trans[pj * 3 + 1], tjz = trans[pj * 3 + 2];
        for (int v = tid; v < V; v += 2048) {
            int v2 = v + 1024;
            bool has2 = (v2 < V);
            float wx1 = vj[3 * v + 0] + tjx;
            float wy1 = vj[3 * v + 1] + tjy;
            float wz1 = vj[3 * v + 2] + tjz;
            float wx2 = 0.0f, wy2 = 0.0f, wz2 = 0.0f;
            if (has2) {
                wx2 = vj[3 * v2 + 0] + tjx;
                wy2 = vj[3 * v2 + 1] + tjy;
                wz2 = vj[3 * v2 + 2] + tjz;
            }
            #define SAMPLE(WX, WY, WZ, COND)                                        \
            do { if (COND) {                                                        \
                float gx = fminf(fmaxf(((WX - cx) / s + 1.0f) * 15.5f, 0.0f), 31.0f);\
                int x0 = min((int)gx, 30);                                          \
                if ((x0 >> 2) == q) {                                               \
                    float gy = fminf(fmaxf(((WY - cy) / s + 1.0f) * 15.5f, 0.0f), 31.0f);\
                    float gz = fminf(fmaxf(((WZ - cz) / s + 1.0f) * 15.5f, 0.0f), 31.0f);\
                    int y0 = min((int)gy, 30);                                      \
                    int z0 = min((int)gz, 30);                                      \
                    float fx = gx - (float)x0;                                      \
                    float fy = gy - (float)y0;                                      \
                    float fz = gz - (float)z0;                                      \
                    int b = ((x0 - xlo) << 10) | (y0 << 5) | z0;                    \
                    float c000 = fmaxf(0.3f - sqrtf(__int_as_float(sgrid[b])), 0.0f);       \
                    float c100 = fmaxf(0.3f - sqrtf(__int_as_float(sgrid[b + 1024])), 0.0f);\
                    float c010 = fmaxf(0.3f - sqrtf(__int_as_float(sgrid[b + 32])), 0.0f);  \
                    float c110 = fmaxf(0.3f - sqrtf(__int_as_float(sgrid[b + 1056])), 0.0f);\
                    float c001 = fmaxf(0.3f - sqrtf(__int_as_float(sgrid[b + 1])), 0.0f);   \
                    float c101 = fmaxf(0.3f - sqrtf(__int_as_float(sgrid[b + 1025])), 0.0f);\
                    float c011 = fmaxf(0.3f - sqrtf(__int_as_float(sgrid[b + 33])), 0.0f);  \
                    float c111 = fmaxf(0.3f - sqrtf(__int_as_float(sgrid[b + 1057])), 0.0f);\
                    float c00 = c000 * (1.0f - fx) + c100 * fx;                     \
                    float c10 = c010 * (1.0f - fx) + c110 * fx;                     \
                    float c01 = c001 * (1.0f - fx) + c101 * fx;                     \
                    float c11 = c011 * (1.0f - fx) + c111 * fx;                     \
                    float c0 = c00 * (1.0f - fy) + c10 * fy;                        \
                    float c1 = c01 * (1.0f - fy) + c11 * fy;                        \
                    float sv = c0 * (1.0f - fz) + c1 * fz;                          \
                    acc += fmaxf(sv, 0.0f);                                         \
                }                                                                   \
            } } while (0)
            SAMPLE(wx1, wy1, wz1, true);
            SAMPLE(wx2, wy2, wz2, has2);
            #undef SAMPLE
        }
    }
    for (int m = 32; m > 0; m >>= 1) acc += __shfl_xor(acc, m);
    if (lane == 0) racc[wave] = acc;
    __syncthreads();
    if (tid == 0) {
        float t = 0.0f;
        for (int w = 0; w < 16; ++w) t += racc[w];
        part[bq] = t;                       // unconditional -> no zero-init
    }
}

// ---------------------------------------------------------------------------
// Final: parallel weighted reduction (R12-proven).
// Harness converts ALL integer inputs to int32 on device.
// ---------------------------------------------------------------------------
__global__ __launch_bounds__(256) void k_final(const float* __restrict__ part,
                                               const int* __restrict__ valid,
                                               const int* __restrict__ pP,
                                               float* __restrict__ out, int n) {
    __shared__ float snum[4], sden[4];
    int P = *pP;
    int F = n / P;
    int tot = n * Q;
    int tid = threadIdx.x, lane = tid & 63, wave = tid >> 6;
    float num = 0.0f;
    for (int i = tid; i < tot; i += 256) {
        int f = i / (P * Q);
        num += part[i] * (float)valid[f * P];
    }
    float den = 0.0f;
    for (int f = tid; f < F; f += 256) den += (float)valid[f * P];
    for (int m = 32; m > 0; m >>= 1) {
        num += __shfl_xor(num, m);
        den += __shfl_xor(den, m);
    }
    if (lane == 0) { snum[wave] = num; sden[wave] = den; }
    __syncthreads();
    if (tid == 0) {
        float tn = snum[0] + snum[1] + snum[2] + snum[3];
        float td = sden[0] + sden[1] + sden[2] + sden[3];
        out[0] = tn / td * (1000.0f / (float)(P * P));
    }
}

// ---------------------------------------------------------------------------
extern "C" void kernel_launch(void* const* d_in, const int* in_sizes, int n_in,
                              void* d_out, int out_size, void* d_ws, size_t ws_size,
                              hipStream_t stream) {
    const float* verts = (const float*)d_in[0];
    const float* trans = (const float*)d_in[1];
    const int*   valid = (const int*)d_in[2];       // int32 on device (harness)
    const int*   pP    = (const int*)d_in[5];       // num_people (device scalar)

    int n = in_sizes[1] / 3;                        // total persons
    int V = in_sizes[0] / in_sizes[1];              // vertices per person

    float* part = (float*)d_ws;                     // n*Q floats

    k_fused<<<n * Q, 1024, 0, stream>>>(verts, trans, part, V, n, pP);
    k_final<<<1, 256, 0, stream>>>(part, valid, pP, (float*)d_out, n);
}